// Round 1
// baseline (154.696 us; speedup 1.0000x reference)
//
#include <hip/hip_runtime.h>
#include <stdint.h>
#include <stddef.h>

#define Tdim 4096
#define Hdim 2048

typedef short short8 __attribute__((ext_vector_type(8)));
typedef float floatx4 __attribute__((ext_vector_type(4)));

// RNE fp32 -> bf16 bit pattern
__device__ __forceinline__ unsigned short f2bf(float f) {
  uint32_t u = __float_as_uint(f);
  u += 0x7fffu + ((u >> 16) & 1u);
  return (unsigned short)(u >> 16);
}

// async global->LDS, 16B per lane. LDS dest must be wave-uniform base + lane*16.
__device__ __forceinline__ void load_lds16(const void* g, void* l) {
  __builtin_amdgcn_global_load_lds(
      (__attribute__((address_space(1))) unsigned int*)(uintptr_t)g,
      (__attribute__((address_space(3))) unsigned int*)l,
      16, 0, 0);
}

// ---- convert x (T*H fp32) -> bf16, 8 elems/thread ----
__global__ __launch_bounds__(256) void cvt_x_kernel(const float* __restrict__ x,
                                                    unsigned short* __restrict__ xbf) {
  size_t i = ((size_t)blockIdx.x * 256 + threadIdx.x) * 8;
  float4 f0 = *(const float4*)(x + i);
  float4 f1 = *(const float4*)(x + i + 4);
  union { unsigned short u[8]; uint4 v; } o;
  o.u[0] = f2bf(f0.x); o.u[1] = f2bf(f0.y); o.u[2] = f2bf(f0.z); o.u[3] = f2bf(f0.w);
  o.u[4] = f2bf(f1.x); o.u[5] = f2bf(f1.y); o.u[6] = f2bf(f1.z); o.u[7] = f2bf(f1.w);
  *(uint4*)(xbf + i) = o.v;
}

// ---- convert + transpose b (HxH fp32, [k][n]) -> bt bf16 (N x K, [n][k]) ----
__global__ __launch_bounds__(256) void cvt_bt_kernel(const float* __restrict__ b,
                                                     unsigned short* __restrict__ bt) {
  __shared__ unsigned short tile[64 * 65];  // +1 pad breaks bank conflicts on transpose read
  const int t = threadIdx.x;
  const int bi = blockIdx.y;  // k block
  const int bj = blockIdx.x;  // n block
#pragma unroll
  for (int p = 0; p < 16; ++p) {
    int r = p * 4 + (t >> 6);
    int c = t & 63;
    tile[r * 65 + c] = f2bf(b[(size_t)(bi * 64 + r) * Hdim + (bj * 64 + c)]);
  }
  __syncthreads();
#pragma unroll
  for (int p = 0; p < 16; ++p) {
    int r2 = p * 4 + (t >> 6);  // n within tile
    int c2 = t & 63;            // k within tile
    bt[(size_t)(bj * 64 + r2) * Hdim + (bi * 64 + c2)] = tile[c2 * 65 + r2];
  }
}

// ---- GEMM: C(MxN fp32) = A(MxK bf16) * B, with B supplied as Bt(NxK bf16) ----
// m97 structure: 128x128 block tile, BK=64, 4 waves in 2x2, each wave 64x64 via
// 4x4 fragments of 16x16x32 MFMA; global_load_lds width-16 staging.
__global__ __launch_bounds__(256) void gemm_bt_kernel(const unsigned short* __restrict__ A,
                                                      const unsigned short* __restrict__ Bt,
                                                      float* __restrict__ C) {
  __shared__ unsigned short sA[128 * 64];
  __shared__ unsigned short sB[128 * 64];
  const int tid = threadIdx.x;
  const int bn = blockIdx.x, bm = blockIdx.y;
  const int wave = tid >> 6, lane = tid & 63;
  const int wm = (wave >> 1) * 64, wn = (wave & 1) * 64;
  const int l15 = lane & 15, quad = lane >> 4;

  // staging source: 8 lanes per row, 16B (8 bf16) per lane, rows advance 32/chunk
  const unsigned short* aSrc = A + ((size_t)(bm * 128 + (tid >> 3)) * Hdim + (tid & 7) * 8);
  const unsigned short* bSrc = Bt + ((size_t)(bn * 128 + (tid >> 3)) * Hdim + (tid & 7) * 8);
  unsigned short* aDst = &sA[tid * 8];
  unsigned short* bDst = &sB[tid * 8];

  floatx4 acc[4][4] = {};

  for (int k0 = 0; k0 < Hdim; k0 += 64) {
#pragma unroll
    for (int c = 0; c < 4; ++c)
      load_lds16(aSrc + (size_t)c * 32 * Hdim + k0, aDst + c * 2048);
#pragma unroll
    for (int c = 0; c < 4; ++c)
      load_lds16(bSrc + (size_t)c * 32 * Hdim + k0, bDst + c * 2048);
    __syncthreads();  // drains vmcnt then barrier -> staging complete
#pragma unroll
    for (int kk = 0; kk < 64; kk += 32) {
      short8 av[4], bv[4];
#pragma unroll
      for (int i = 0; i < 4; ++i)
        av[i] = *(const short8*)&sA[(wm + i * 16 + l15) * 64 + kk + quad * 8];
#pragma unroll
      for (int j = 0; j < 4; ++j)
        bv[j] = *(const short8*)&sB[(wn + j * 16 + l15) * 64 + kk + quad * 8];
#pragma unroll
      for (int i = 0; i < 4; ++i)
#pragma unroll
        for (int j = 0; j < 4; ++j)
          acc[i][j] = __builtin_amdgcn_mfma_f32_16x16x32_bf16(av[i], bv[j], acc[i][j], 0, 0, 0);
    }
    __syncthreads();
  }

  // C/D layout: col = lane&15, row = quad*4 + r (m89/m91-verified)
  const int row0 = bm * 128 + wm + quad * 4;
  const int col0 = bn * 128 + wn + l15;
#pragma unroll
  for (int i = 0; i < 4; ++i)
#pragma unroll
    for (int j = 0; j < 4; ++j)
#pragma unroll
      for (int r = 0; r < 4; ++r)
        C[(size_t)(row0 + i * 16 + r) * Hdim + (col0 + j * 16)] = acc[i][j][r];
}

// ---- windowed parallel "scan": |a| <= 0.03125 so influence of h_{t-8} < 1e-12 ----
__device__ __forceinline__ float tanh_fast(float z) {
  // tanh(z) = 1 - 2/(exp(2z)+1); safe for all z (overflow -> 1, underflow -> -1)
  float e = __expf(z + z);
  return 1.0f - __fdividef(2.0f, e + 1.0f);
}

__global__ __launch_bounds__(256) void scan_kernel(const float* __restrict__ s,
                                                   const float* __restrict__ a,
                                                   float* __restrict__ out) {
  const int j = blockIdx.x * 256 + threadIdx.x;  // column
  const int t0 = blockIdx.y * 32;                // output chunk start
  const float aj = a[j];
  float h = 0.0f;
  int ts = t0 - 8;
  if (ts < 0) ts = 0;
  for (int t = ts; t < t0; ++t)  // warm-up window (exact for t0==0)
    h = tanh_fast(fmaf(aj, h, s[(size_t)t * Hdim + j]));
#pragma unroll
  for (int t = t0; t < t0 + 32; ++t) {
    h = tanh_fast(fmaf(aj, h, s[(size_t)t * Hdim + j]));
    out[(size_t)t * Hdim + j] = h;
  }
}

extern "C" void kernel_launch(void* const* d_in, const int* in_sizes, int n_in,
                              void* d_out, int out_size, void* d_ws, size_t ws_size,
                              hipStream_t stream) {
  const float* x = (const float*)d_in[0];
  const float* a = (const float*)d_in[1];
  const float* b = (const float*)d_in[2];
  float* out = (float*)d_out;

  char* ws = (char*)d_ws;
  float* s = (float*)ws;                                            // 33.5 MB
  unsigned short* xbf = (unsigned short*)(ws + (size_t)Tdim * Hdim * 4);  // 16.8 MB
  unsigned short* btb = xbf + (size_t)Tdim * Hdim;                  // 8.4 MB

  hipLaunchKernelGGL(cvt_x_kernel, dim3((Tdim * Hdim) / (256 * 8)), dim3(256), 0, stream,
                     x, xbf);
  hipLaunchKernelGGL(cvt_bt_kernel, dim3(Hdim / 64, Hdim / 64), dim3(256), 0, stream,
                     b, btb);
  hipLaunchKernelGGL(gemm_bt_kernel, dim3(Hdim / 128, Tdim / 128), dim3(256), 0, stream,
                     xbf, btb, s);
  hipLaunchKernelGGL(scan_kernel, dim3(Hdim / 256, Tdim / 32), dim3(256), 0, stream,
                     s, a, out);
}